// Round 14
// baseline (1088.937 us; speedup 1.0000x reference)
//
#include <hip/hip_runtime.h>
#include <math.h>

#define NGRAPH 500
#define MP_STEPS 6
#define S2S_STEPS 6
#define S2S_CAP 128

typedef _Float16 h8 __attribute__((ext_vector_type(8)));
typedef float f4 __attribute__((ext_vector_type(4)));

__device__ __forceinline__ float sigmoidf_(float v){ return 1.0f/(1.0f + expf(-v)); }

// ---------------- generic zero fill ----------------
__global__ void k_zero(float* __restrict__ p, int n){
  int i = blockIdx.x*256 + threadIdx.x;
  if(i < n) p[i] = 0.f;
}

// ---------------- initial node embedding: x = relu(nf @ lin0_W + b) ----------------
__global__ void k_lin0(const float* __restrict__ nf, const float* __restrict__ W,
                       const float* __restrict__ b, float* __restrict__ x, int N){
  int n = blockIdx.x*4 + (threadIdx.x >> 6);
  int d = threadIdx.x & 63;
  if(n >= N) return;
  float acc = b[d];
#pragma unroll
  for(int i=0;i<15;i++) acc = fmaf(nf[n*15+i], W[i*64+d], acc);
  x[n*64+d] = fmaxf(acc, 0.0f);
}

// ---------------- edge hidden: he_h[e][0..127] = relu(ef@W1+b1), [128]=1, [129..159]=0 ----
__global__ void k_edgeh(const float* __restrict__ ef, const float* __restrict__ W1,
                        const float* __restrict__ b1, _Float16* __restrict__ he, int E){
  int e = blockIdx.x;
  int h = threadIdx.x;   // block 192
  if(e >= E || h >= 160) return;
  float v;
  if(h < 128){
    float acc = b1[h];
#pragma unroll
    for(int i=0;i<5;i++) acc = fmaf(ef[e*5+i], W1[i*128+h], acc);
    v = fmaxf(acc, 0.f);
  } else {
    v = (h == 128) ? 1.0f : 0.0f;
  }
  he[(size_t)e*160 + h] = (_Float16)v;
}

// ---------------- W2T[n][k] (f16): k<128 -> em_W2[k][n]; k==128 -> b2[n]; else 0 ----------
__global__ void k_prepW2(const float* __restrict__ W2, const float* __restrict__ b2,
                         _Float16* __restrict__ W2T){
  int idx = blockIdx.x*256 + threadIdx.x;
  if(idx >= 4096*160) return;
  int n = idx / 160, k = idx % 160;
  float v = (k < 128) ? W2[(size_t)k*4096 + n] : ((k == 128) ? b2[n] : 0.f);
  W2T[idx] = (_Float16)v;
}

// ---------------- fused message: agg[dst[e]] += x[src[e]] . (he[e] @ W2') ----------------
// R10: exact R7 structure (best verified: 100.8us. 128 edges, 8 waves = 2 edge-halves
// x 4 col-groups, af[4][5] in regs, register double-buffered B-prefetch) + one change:
// raw s_barrier per i to keep mrow-twin waves (0,4)(1,5)(2,6)(3,7) in lockstep so the
// twin's identical B-loads hit L1 (32KB/CU; B-stream 20KB/i) -> halves L2 B-traffic
// (was 40KB/i/CU = 730cyc vs 776cyc matrix, i.e. co-binding). Raw barrier does NOT
// drain vmcnt (unlike __syncthreads) so the prefetch stays in flight (m139 pattern).
// R9 lesson: af-in-LDS costs 16M bank conflicts (b128 column reads can't be pad-fixed).
// R8 lesson: removing the B-prefetch is -76%. R4-lesson: (512,2) cap 256 >> ~190 need.
__global__ __launch_bounds__(512, 2) void k_fmsg(
    const _Float16* __restrict__ he,   // [E][160]
    const _Float16* __restrict__ W2T,  // [4096][160]
    const float* __restrict__ x,       // [N][64]
    const int* __restrict__ src, const int* __restrict__ dst,
    float* __restrict__ agg, int E)
{
  __shared__ _Float16 hs[128*160];   // 40 KB
  __shared__ float xsT[64*132];      // 33.8 KB: [dim][edge slot], stride 132
  __shared__ int ds_dst[128];
  const int tid  = threadIdx.x;
  const int wave = tid >> 6;         // 0..7
  const int mrow = wave >> 2;        // 0..1: which 64-edge half
  const int cg   = wave & 3;         // 0..3: output col group
  const int lane = tid & 63;
  const int quad = lane >> 4;
  const int l15  = lane & 15;
  const int e0   = blockIdx.x * 128;

  // he staging: 128 rows x 20 uint4
  for(int t = tid; t < 2560; t += 512){
    int r = t / 20, c = t % 20;
    uint4 v = make_uint4(0,0,0,0);
    if(e0 + r < E) v = *(const uint4*)&he[(size_t)(e0+r)*160 + c*8];
    *(uint4*)&hs[r*160 + c*8] = v;
  }
  // x gather -> xsT: j = edge slot 0..127, qc = quarter of dims
  {
    int j = tid >> 2, qc = tid & 3;
    int sj = (e0 + j < E) ? src[e0 + j] : 0;
    const float4* xr = (const float4*)(x + (size_t)sj*64);
#pragma unroll
    for(int k=0;k<4;k++){
      float4 v = xr[qc*4 + k];
      int ib = qc*16 + k*4;
      xsT[(ib+0)*132 + j] = v.x;
      xsT[(ib+1)*132 + j] = v.y;
      xsT[(ib+2)*132 + j] = v.z;
      xsT[(ib+3)*132 + j] = v.w;
    }
  }
  if(tid < 128) ds_dst[tid] = (e0 + tid < E) ? dst[e0 + tid] : 0;
  __syncthreads();

  // A fragments: this wave's 64-edge half, 4 tiles of 16 edges (in registers — R7)
  h8 af[4][5];
#pragma unroll
  for(int mt=0;mt<4;mt++)
#pragma unroll
    for(int ks=0;ks<5;ks++)
      af[mt][ks] = *(const h8*)&hs[(mrow*64 + mt*16 + l15)*160 + ks*32 + (quad<<3)];

  const _Float16* bbase = W2T + ((size_t)(cg*16 + l15))*160 + (quad<<3);
  h8 bf[5], bn[5];
#pragma unroll
  for(int ks=0;ks<5;ks++) bf[ks] = *(const h8*)(bbase + ks*32);

  f4 macc[4];
#pragma unroll
  for(int mt=0;mt<4;mt++) macc[mt] = (f4){0.f,0.f,0.f,0.f};

#pragma unroll 2
  for(int i=0;i<64;i++){
    if(i < 63){
      const _Float16* nb = bbase + (size_t)(i+1)*64*160;
#pragma unroll
      for(int ks=0;ks<5;ks++) bn[ks] = *(const h8*)(nb + ks*32);
    }
    f4 g0 = (f4){0.f,0.f,0.f,0.f}, g1 = g0, g2 = g0, g3 = g0;
#pragma unroll
    for(int ks=0;ks<5;ks++){
      g0 = __builtin_amdgcn_mfma_f32_16x16x32_f16(af[0][ks], bf[ks], g0, 0, 0, 0);
      g1 = __builtin_amdgcn_mfma_f32_16x16x32_f16(af[1][ks], bf[ks], g1, 0, 0, 0);
      g2 = __builtin_amdgcn_mfma_f32_16x16x32_f16(af[2][ks], bf[ks], g2, 0, 0, 0);
      g3 = __builtin_amdgcn_mfma_f32_16x16x32_f16(af[3][ks], bf[ks], g3, 0, 0, 0);
    }
    f4 xs0 = *(const f4*)&xsT[i*132 + mrow*64 + (quad<<2) +  0];
    f4 xs1 = *(const f4*)&xsT[i*132 + mrow*64 + (quad<<2) + 16];
    f4 xs2 = *(const f4*)&xsT[i*132 + mrow*64 + (quad<<2) + 32];
    f4 xs3 = *(const f4*)&xsT[i*132 + mrow*64 + (quad<<2) + 48];
    macc[0] += xs0 * g0;
    macc[1] += xs1 * g1;
    macc[2] += xs2 * g2;
    macc[3] += xs3 * g3;
#pragma unroll
    for(int ks=0;ks<5;ks++) bf[ks] = bn[ks];
    // pace the 8 waves so mrow-twins stream the same B window -> L1 hits.
    // raw barrier: no vmcnt drain, prefetch stays in flight.
    __builtin_amdgcn_s_barrier();
  }

  const int col = cg*16 + l15;
#pragma unroll
  for(int mt=0;mt<4;mt++){
#pragma unroll
    for(int r=0;r<4;r++){
      int edge = mrow*64 + mt*16 + (quad<<2) + r;
      if(e0 + edge < E)
        atomicAdd(&agg[(size_t)ds_dst[edge]*64 + col], macc[mt][r]);
    }
  }
}

// ---------------- GRU: 32 nodes/block ----------------
__global__ __launch_bounds__(256) void k_gru2(
    float* __restrict__ x, float* __restrict__ agg, const float* __restrict__ cb,
    const float* __restrict__ WihT, const float* __restrict__ WhhT,   // [64][192]
    const float* __restrict__ bih, const float* __restrict__ bhh, int N)
{
  __shared__ float ms[32*64], hs2[32*64];
  const int tid = threadIdx.x;
  const int n0 = blockIdx.x*32;
  for(int t=tid; t<2048; t+=256){
    int n = n0 + (t>>6), d = t&63;
    float mv=0.f, hv=0.f;
    if(n < N){
      mv = fmaxf(agg[(size_t)n*64+d] + cb[d], 0.f);
      agg[(size_t)n*64+d] = 0.f;
      hv = x[(size_t)n*64+d];
    }
    ms[t]=mv; hs2[t]=hv;
  }
  __syncthreads();
  const int gx = tid & 31, ng = tid >> 5;
  float ar[4][2]={{0}}, az[4][2]={{0}}, anx[4][2]={{0}}, anh[4][2]={{0}};
#pragma unroll 4
  for(int k=0;k<64;k++){
    float wi0=WihT[k*192+gx],     wi1=WihT[k*192+gx+32];
    float wi2=WihT[k*192+gx+64],  wi3=WihT[k*192+gx+96];
    float wi4=WihT[k*192+gx+128], wi5=WihT[k*192+gx+160];
    float wh0=WhhT[k*192+gx],     wh1=WhhT[k*192+gx+32];
    float wh2=WhhT[k*192+gx+64],  wh3=WhhT[k*192+gx+96];
    float wh4=WhhT[k*192+gx+128], wh5=WhhT[k*192+gx+160];
#pragma unroll
    for(int j=0;j<4;j++){
      float mk = ms[(ng*4+j)*64+k], hk = hs2[(ng*4+j)*64+k];
      ar[j][0] = fmaf(mk,wi0, fmaf(hk,wh0, ar[j][0]));
      ar[j][1] = fmaf(mk,wi1, fmaf(hk,wh1, ar[j][1]));
      az[j][0] = fmaf(mk,wi2, fmaf(hk,wh2, az[j][0]));
      az[j][1] = fmaf(mk,wi3, fmaf(hk,wh3, az[j][1]));
      anx[j][0]= fmaf(mk,wi4, anx[j][0]);
      anx[j][1]= fmaf(mk,wi5, anx[j][1]);
      anh[j][0]= fmaf(hk,wh4, anh[j][0]);
      anh[j][1]= fmaf(hk,wh5, anh[j][1]);
    }
  }
#pragma unroll
  for(int j=0;j<4;j++){
    int n = n0 + ng*4 + j;
    if(n >= N) continue;
#pragma unroll
    for(int c=0;c<2;c++){
      int d = gx + 32*c;
      float r  = sigmoidf_(ar[j][c] + bih[d]     + bhh[d]);
      float z  = sigmoidf_(az[j][c] + bih[64+d]  + bhh[64+d]);
      float nn = tanhf(anx[j][c] + bih[128+d] + r*(anh[j][c] + bhh[128+d]));
      float hv = hs2[(ng*4+j)*64+d];
      x[(size_t)n*64+d] = (1.f - z)*nn + z*hv;
    }
  }
}

// ---------------- weight transposes ----------------
__global__ void k_tr_gru(const float* __restrict__ Wih, const float* __restrict__ Whh,
                         float* __restrict__ WihT, float* __restrict__ WhhT){
  int idx = blockIdx.x*256 + threadIdx.x;
  if(idx < 192*64){
    int r = idx/64, i = idx%64;
    WihT[i*192 + r] = Wih[idx];
    WhhT[i*192 + r] = Whh[idx];
  }
}

// LSTM weights as concatenated [Wih | Whh] along k, transposed to [k][256]
__global__ void k_tr_lstmcat(const float* __restrict__ w0ih, const float* __restrict__ w0hh,
                             const float* __restrict__ w12ih, const float* __restrict__ w12hh,
                             float* __restrict__ W0cat, float* __restrict__ W12cat){
  int idx = blockIdx.x*256 + threadIdx.x;
  if(idx < 192*256){
    int k = idx / 256, r = idx % 256;
    W0cat[idx] = (k < 128) ? w0ih[r*128 + k] : w0hh[r*64 + (k - 128)];
  }
  if(idx < 2*128*256){
    int l = idx / (128*256);
    int rem = idx % (128*256);
    int k = rem / 256, r = rem % 256;
    W12cat[idx] = (k < 64) ? w12ih[((size_t)l*256 + r)*64 + k]
                           : w12hh[((size_t)l*256 + r)*64 + (k - 64)];
  }
}

// ---------------- fused Set2Set + head ----------------
__device__ __forceinline__ int lbound(const int* __restrict__ a, int n, int v){
  int lo=0, hi=n;
  while(lo<hi){ int mid=(lo+hi)>>1; if(a[mid]<v) lo=mid+1; else hi=mid; }
  return lo;
}

template<int KTOT>
__device__ __forceinline__ void lstm_layer2(
    const float* __restrict__ xin, float* __restrict__ hv, float* __restrict__ cv,
    const float* __restrict__ Wcat, const float* __restrict__ bsum,
    f4* __restrict__ ps4, int t)
{
  constexpr int CH = KTOT/4;
  const int kc = t >> 6, tq = t & 63;
  const float* wp = Wcat + (size_t)(kc*CH)*256 + 4*tq;
  const float* xp = xin + kc*CH;
  f4 acc = (f4){0.f,0.f,0.f,0.f};
#pragma unroll
  for(int i=0;i<CH;i++){
    f4 w = *(const f4*)(wp + (size_t)i*256);
    acc += xp[i] * w;
  }
  ps4[t] = acc;
  __syncthreads();
  if(t < 64){
    float v[4];
#pragma unroll
    for(int g=0; g<4; g++){
      int G = g*64 + t;
      int q = G >> 2, cmp = G & 3;
      float s = 0.f;
#pragma unroll
      for(int k2=0; k2<4; k2++) s += ps4[k2*64 + q][cmp];
      v[g] = s + bsum[G];
    }
    float ig = sigmoidf_(v[0]);
    float fg = sigmoidf_(v[1]);
    float gg = tanhf(v[2]);
    float og = sigmoidf_(v[3]);
    float cn = fg*cv[t] + ig*gg;
    cv[t] = cn;
    hv[t] = og*tanhf(cn);
  }
  __syncthreads();
}

__global__ __launch_bounds__(256) void k_s2s(
    const float* __restrict__ x, const int* __restrict__ gid, int N,
    const float* __restrict__ W0cat, const float* __restrict__ W12cat,
    const float* __restrict__ l0_bih, const float* __restrict__ l0_bhh,
    const float* __restrict__ l12_bih, const float* __restrict__ l12_bhh,
    const float* __restrict__ W1, const float* __restrict__ b1,
    const float* __restrict__ W2, const float* __restrict__ b2,
    float* __restrict__ y)
{
  const int b = blockIdx.x;
  const int t = threadIdx.x;
  const int wave = t >> 6, lane = t & 63;
  __shared__ float xt[S2S_CAP*65];
  __shared__ float qcat[320];
  __shared__ float csl[192];
  __shared__ f4    ps4[256];
  __shared__ float bsum[768];
  __shared__ float ps[S2S_CAP];
  __shared__ float rop[256];
  __shared__ float wred[4], wsum[4];
  __shared__ int sh_n0, sh_n1;

  if(t == 0) sh_n0 = lbound(gid, N, b);
  if(t == 1) sh_n1 = lbound(gid, N, b+1);
  for(int i=t; i<320; i+=256) qcat[i] = 0.f;
  if(t < 192) csl[t] = 0.f;
  for(int i=t; i<768; i+=256){
    int layer = i >> 8, g = i & 255;
    float bi, bh;
    if(layer == 0){ bi = l0_bih[g]; bh = l0_bhh[g]; }
    else { bi = l12_bih[(layer-1)*256+g]; bh = l12_bhh[(layer-1)*256+g]; }
    bsum[i] = bi + bh;
  }
  __syncthreads();
  const int n0 = sh_n0, cnt = sh_n1 - sh_n0;
  const int cc = (cnt < S2S_CAP) ? cnt : S2S_CAP;

  for(int j = wave; j < cc; j += 4)
    xt[j*65 + lane] = x[(size_t)(n0+j)*64 + lane];
  __syncthreads();

  for(int step=0; step<S2S_STEPS; step++){
    lstm_layer2<192>(qcat,       qcat+128, csl,     W0cat,            bsum,       ps4, t);
    lstm_layer2<128>(qcat+128,   qcat+192, csl+64,  W12cat,           bsum+256,   ps4, t);
    lstm_layer2<128>(qcat+192,   qcat+256, csl+128, W12cat+128*256,   bsum+512,   ps4, t);

    const float* q = qcat + 256;    // h2
    float accd = 0.f;
    if(t < cc){
      const float* xr = xt + t*65;
#pragma unroll 8
      for(int k=0;k<64;k++) accd = fmaf(xr[k], q[k], accd);
    }
    float pm = (t < cc) ? accd : -1e30f;
    float qv = q[lane];
    for(int j = S2S_CAP + wave; j < cnt; j += 4){   // fallback (rare)
      float p = x[(size_t)(n0+j)*64 + lane] * qv;
#pragma unroll
      for(int o=32;o;o>>=1) p += __shfl_xor(p, o, 64);
      pm = fmaxf(pm, p);
    }
#pragma unroll
    for(int o=32;o;o>>=1) pm = fmaxf(pm, __shfl_xor(pm, o, 64));
    if(lane == 0) wred[wave] = pm;
    __syncthreads();
    float mx = fmaxf(fmaxf(wred[0],wred[1]), fmaxf(wred[2],wred[3]));

    float ex = 0.f;
    if(t < cc){ ex = expf(accd - mx); ps[t] = ex; }
    float exsum = ex;
    float racc = 0.f;
    for(int j = S2S_CAP + wave; j < cnt; j += 4){   // fallback (rare)
      float xv = x[(size_t)(n0+j)*64 + lane];
      float p = xv * qv;
#pragma unroll
      for(int o=32;o;o>>=1) p += __shfl_xor(p, o, 64);
      float e2 = expf(p - mx);
      if(lane == 0) exsum += e2;
      racc = fmaf(e2, xv, racc);
    }
#pragma unroll
    for(int o=32;o;o>>=1) exsum += __shfl_xor(exsum, o, 64);
    if(lane == 0) wsum[wave] = exsum;
    __syncthreads();

    for(int j = wave; j < cc; j += 4)
      racc = fmaf(ps[j], xt[j*65 + lane], racc);
    rop[wave*64 + lane] = racc;
    __syncthreads();
    if(t < 64){
      float tot = wsum[0]+wsum[1]+wsum[2]+wsum[3];
      float inv = (tot > 0.f) ? 1.f/tot : 0.f;
      float rv = (rop[t] + rop[64+t] + rop[128+t] + rop[192+t]) * inv;
      qcat[t] = qcat[256+t];
      qcat[64+t] = rv;
    }
    __syncthreads();
  }
  // ---- head ----
  if(t < 64){
    float a = b1[t];
#pragma unroll 4
    for(int k=0;k<128;k++) a = fmaf(qcat[k], W1[k*64+t], a);
    rop[t] = fmaxf(a, 0.f);
  }
  __syncthreads();
  if(t < 12){
    float o = b2[t];
#pragma unroll 4
    for(int k=0;k<64;k++) o = fmaf(rop[k], W2[k*12+t], o);
    y[b*12+t] = o;
  }
}

extern "C" void kernel_launch(void* const* d_in, const int* in_sizes, int n_in,
                              void* d_out, int out_size, void* d_ws, size_t ws_size,
                              hipStream_t stream) {
  const float* node_feat = (const float*)d_in[0];
  const float* edge_feat = (const float*)d_in[1];
  const int*   src       = (const int*)d_in[2];
  const int*   dst       = (const int*)d_in[3];
  const int*   gid       = (const int*)d_in[4];
  const float* lin0_W = (const float*)d_in[6];
  const float* lin0_b = (const float*)d_in[7];
  const float* em_W1  = (const float*)d_in[8];
  const float* em_b1  = (const float*)d_in[9];
  const float* em_W2  = (const float*)d_in[10];
  const float* em_b2  = (const float*)d_in[11];
  const float* conv_b = (const float*)d_in[12];
  const float* gru_Wih = (const float*)d_in[13];
  const float* gru_Whh = (const float*)d_in[14];
  const float* gru_bih = (const float*)d_in[15];
  const float* gru_bhh = (const float*)d_in[16];
  const float* l0_Wih = (const float*)d_in[17];
  const float* l0_Whh = (const float*)d_in[18];
  const float* l0_bih = (const float*)d_in[19];
  const float* l0_bhh = (const float*)d_in[20];
  const float* l12_Wih = (const float*)d_in[21];
  const float* l12_Whh = (const float*)d_in[22];
  const float* l12_bih = (const float*)d_in[23];
  const float* l12_bhh = (const float*)d_in[24];
  const float* lin1_W = (const float*)d_in[25];
  const float* lin1_b = (const float*)d_in[26];
  const float* lin2_W = (const float*)d_in[27];
  const float* lin2_b = (const float*)d_in[28];
  float* y = (float*)d_out;

  const int N = in_sizes[0] / 15;
  const int E = in_sizes[1] / 5;
  const int B = NGRAPH;

  char* p = (char*)d_ws;
  auto carve = [&](size_t bytes)->char* {
    char* r = p; p += (bytes + 255) & ~(size_t)255; return r;
  };
  _Float16* he_h = (_Float16*)carve((size_t)E*160*2);
  _Float16* W2T  = (_Float16*)carve((size_t)4096*160*2);
  float* x      = (float*)carve((size_t)N*64*4);
  float* agg    = (float*)carve((size_t)N*64*4);
  float* gWihT  = (float*)carve(192*64*4);
  float* gWhhT  = (float*)carve(192*64*4);
  float* W0cat  = (float*)carve(192*256*4);
  float* W12cat = (float*)carve(2*128*256*4);
  (void)ws_size; (void)n_in; (void)out_size;

  // ---- prep ----
  k_lin0<<<(N+3)/4, 256, 0, stream>>>(node_feat, lin0_W, lin0_b, x, N);
  k_edgeh<<<E, 192, 0, stream>>>(edge_feat, em_W1, em_b1, he_h, E);
  k_prepW2<<<(4096*160+255)/256, 256, 0, stream>>>(em_W2, em_b2, W2T);
  k_tr_gru<<<(192*64+255)/256, 256, 0, stream>>>(gru_Wih, gru_Whh, gWihT, gWhhT);
  k_tr_lstmcat<<<(2*128*256+255)/256, 256, 0, stream>>>(l0_Wih, l0_Whh, l12_Wih, l12_Whh,
                                                        W0cat, W12cat);
  k_zero<<<(N*64+255)/256, 256, 0, stream>>>(agg, N*64);

  // ---- message passing (k_gru2 zeroes agg for the next step) ----
  const int nblk = (E + 127) / 128;
  for(int s=0; s<MP_STEPS; s++){
    k_fmsg<<<nblk, 512, 0, stream>>>(he_h, W2T, x, src, dst, agg, E);
    k_gru2<<<(N+31)/32, 256, 0, stream>>>(x, agg, conv_b, gWihT, gWhhT, gru_bih, gru_bhh, N);
  }

  // ---- fused set2set + head ----
  k_s2s<<<B, 256, 0, stream>>>(x, gid, N,
                               W0cat, W12cat, l0_bih, l0_bhh,
                               l12_bih, l12_bhh,
                               lin1_W, lin1_b, lin2_W, lin2_b, y);
}

// Round 15
// 905.725 us; speedup vs baseline: 1.2023x; 1.2023x over previous
//
#include <hip/hip_runtime.h>
#include <math.h>

#define NGRAPH 500
#define MP_STEPS 6
#define S2S_STEPS 6
#define S2S_CAP 64   // per-graph node cap in k_s2s (max bin ~36 at N=10000,B=500; 9-sigma safe)

typedef _Float16 h8 __attribute__((ext_vector_type(8)));
typedef float f4 __attribute__((ext_vector_type(4)));

__device__ __forceinline__ float sigmoidf_(float v){ return 1.0f/(1.0f + expf(-v)); }

// ---------------- generic zero fill ----------------
__global__ void k_zero(float* __restrict__ p, int n){
  int i = blockIdx.x*256 + threadIdx.x;
  if(i < n) p[i] = 0.f;
}

// ---------------- initial node embedding: x = relu(nf @ lin0_W + b) ----------------
__global__ void k_lin0(const float* __restrict__ nf, const float* __restrict__ W,
                       const float* __restrict__ b, float* __restrict__ x, int N){
  int n = blockIdx.x*4 + (threadIdx.x >> 6);
  int d = threadIdx.x & 63;
  if(n >= N) return;
  float acc = b[d];
#pragma unroll
  for(int i=0;i<15;i++) acc = fmaf(nf[n*15+i], W[i*64+d], acc);
  x[n*64+d] = fmaxf(acc, 0.0f);
}

// ---------------- edge hidden: he_h[e][0..127] = relu(ef@W1+b1), [128]=1, [129..159]=0 ----
__global__ void k_edgeh(const float* __restrict__ ef, const float* __restrict__ W1,
                        const float* __restrict__ b1, _Float16* __restrict__ he, int E){
  int e = blockIdx.x;
  int h = threadIdx.x;   // block 192
  if(e >= E || h >= 160) return;
  float v;
  if(h < 128){
    float acc = b1[h];
#pragma unroll
    for(int i=0;i<5;i++) acc = fmaf(ef[e*5+i], W1[i*128+h], acc);
    v = fmaxf(acc, 0.f);
  } else {
    v = (h == 128) ? 1.0f : 0.0f;
  }
  he[(size_t)e*160 + h] = (_Float16)v;
}

// ---------------- W2T[n][k] (f16): k<128 -> em_W2[k][n]; k==128 -> b2[n]; else 0 ----------
__global__ void k_prepW2(const float* __restrict__ W2, const float* __restrict__ b2,
                         _Float16* __restrict__ W2T){
  int idx = blockIdx.x*256 + threadIdx.x;
  if(idx >= 4096*160) return;
  int n = idx / 160, k = idx % 160;
  float v = (k < 128) ? W2[(size_t)k*4096 + n] : ((k == 128) ? b2[n] : 0.f);
  W2T[idx] = (_Float16)v;
}

// ---------------- fused message: agg[dst[e]] += x[src[e]] . (he[e] @ W2') ----------------
// R15: EXACT R7 structure (verified best 100.8us): 128 edges, 8 waves = 2 edge-halves
// x 4 col-groups, af[4][5] in regs, register double-buffered B-prefetch.
// R14 lesson: per-i raw s_barrier twin-pacing = +25% regression (throttles prefetch,
// no L1 sharing materialized). R9: af-in-LDS = 16M bank conflicts. R8: no prefetch = -76%.
// R4: never cap VGPR below need -> (512,2).
__global__ __launch_bounds__(512, 2) void k_fmsg(
    const _Float16* __restrict__ he,   // [E][160]
    const _Float16* __restrict__ W2T,  // [4096][160]
    const float* __restrict__ x,       // [N][64]
    const int* __restrict__ src, const int* __restrict__ dst,
    float* __restrict__ agg, int E)
{
  __shared__ _Float16 hs[128*160];   // 40 KB
  __shared__ float xsT[64*132];      // 33.8 KB: [dim][edge slot], stride 132
  __shared__ int ds_dst[128];
  const int tid  = threadIdx.x;
  const int wave = tid >> 6;         // 0..7
  const int mrow = wave >> 2;        // 0..1: which 64-edge half
  const int cg   = wave & 3;         // 0..3: output col group
  const int lane = tid & 63;
  const int quad = lane >> 4;
  const int l15  = lane & 15;
  const int e0   = blockIdx.x * 128;

  for(int t = tid; t < 2560; t += 512){
    int r = t / 20, c = t % 20;
    uint4 v = make_uint4(0,0,0,0);
    if(e0 + r < E) v = *(const uint4*)&he[(size_t)(e0+r)*160 + c*8];
    *(uint4*)&hs[r*160 + c*8] = v;
  }
  {
    int j = tid >> 2, qc = tid & 3;
    int sj = (e0 + j < E) ? src[e0 + j] : 0;
    const float4* xr = (const float4*)(x + (size_t)sj*64);
#pragma unroll
    for(int k=0;k<4;k++){
      float4 v = xr[qc*4 + k];
      int ib = qc*16 + k*4;
      xsT[(ib+0)*132 + j] = v.x;
      xsT[(ib+1)*132 + j] = v.y;
      xsT[(ib+2)*132 + j] = v.z;
      xsT[(ib+3)*132 + j] = v.w;
    }
  }
  if(tid < 128) ds_dst[tid] = (e0 + tid < E) ? dst[e0 + tid] : 0;
  __syncthreads();

  h8 af[4][5];
#pragma unroll
  for(int mt=0;mt<4;mt++)
#pragma unroll
    for(int ks=0;ks<5;ks++)
      af[mt][ks] = *(const h8*)&hs[(mrow*64 + mt*16 + l15)*160 + ks*32 + (quad<<3)];

  const _Float16* bbase = W2T + ((size_t)(cg*16 + l15))*160 + (quad<<3);
  h8 bf[5], bn[5];
#pragma unroll
  for(int ks=0;ks<5;ks++) bf[ks] = *(const h8*)(bbase + ks*32);

  f4 macc[4];
#pragma unroll
  for(int mt=0;mt<4;mt++) macc[mt] = (f4){0.f,0.f,0.f,0.f};

#pragma unroll 2
  for(int i=0;i<64;i++){
    if(i < 63){
      const _Float16* nb = bbase + (size_t)(i+1)*64*160;
#pragma unroll
      for(int ks=0;ks<5;ks++) bn[ks] = *(const h8*)(nb + ks*32);
    }
    f4 g0 = (f4){0.f,0.f,0.f,0.f}, g1 = g0, g2 = g0, g3 = g0;
#pragma unroll
    for(int ks=0;ks<5;ks++){
      g0 = __builtin_amdgcn_mfma_f32_16x16x32_f16(af[0][ks], bf[ks], g0, 0, 0, 0);
      g1 = __builtin_amdgcn_mfma_f32_16x16x32_f16(af[1][ks], bf[ks], g1, 0, 0, 0);
      g2 = __builtin_amdgcn_mfma_f32_16x16x32_f16(af[2][ks], bf[ks], g2, 0, 0, 0);
      g3 = __builtin_amdgcn_mfma_f32_16x16x32_f16(af[3][ks], bf[ks], g3, 0, 0, 0);
    }
    f4 xs0 = *(const f4*)&xsT[i*132 + mrow*64 + (quad<<2) +  0];
    f4 xs1 = *(const f4*)&xsT[i*132 + mrow*64 + (quad<<2) + 16];
    f4 xs2 = *(const f4*)&xsT[i*132 + mrow*64 + (quad<<2) + 32];
    f4 xs3 = *(const f4*)&xsT[i*132 + mrow*64 + (quad<<2) + 48];
    macc[0] += xs0 * g0;
    macc[1] += xs1 * g1;
    macc[2] += xs2 * g2;
    macc[3] += xs3 * g3;
#pragma unroll
    for(int ks=0;ks<5;ks++) bf[ks] = bn[ks];
  }

  const int col = cg*16 + l15;
#pragma unroll
  for(int mt=0;mt<4;mt++){
#pragma unroll
    for(int r=0;r<4;r++){
      int edge = mrow*64 + mt*16 + (quad<<2) + r;
      if(e0 + edge < E)
        atomicAdd(&agg[(size_t)ds_dst[edge]*64 + col], macc[mt][r]);
    }
  }
}

// ---------------- GRU: 32 nodes/block ----------------
__global__ __launch_bounds__(256) void k_gru2(
    float* __restrict__ x, float* __restrict__ agg, const float* __restrict__ cb,
    const float* __restrict__ WihT, const float* __restrict__ WhhT,   // [64][192]
    const float* __restrict__ bih, const float* __restrict__ bhh, int N)
{
  __shared__ float ms[32*64], hs2[32*64];
  const int tid = threadIdx.x;
  const int n0 = blockIdx.x*32;
  for(int t=tid; t<2048; t+=256){
    int n = n0 + (t>>6), d = t&63;
    float mv=0.f, hv=0.f;
    if(n < N){
      mv = fmaxf(agg[(size_t)n*64+d] + cb[d], 0.f);
      agg[(size_t)n*64+d] = 0.f;
      hv = x[(size_t)n*64+d];
    }
    ms[t]=mv; hs2[t]=hv;
  }
  __syncthreads();
  const int gx = tid & 31, ng = tid >> 5;
  float ar[4][2]={{0}}, az[4][2]={{0}}, anx[4][2]={{0}}, anh[4][2]={{0}};
#pragma unroll 4
  for(int k=0;k<64;k++){
    float wi0=WihT[k*192+gx],     wi1=WihT[k*192+gx+32];
    float wi2=WihT[k*192+gx+64],  wi3=WihT[k*192+gx+96];
    float wi4=WihT[k*192+gx+128], wi5=WihT[k*192+gx+160];
    float wh0=WhhT[k*192+gx],     wh1=WhhT[k*192+gx+32];
    float wh2=WhhT[k*192+gx+64],  wh3=WhhT[k*192+gx+96];
    float wh4=WhhT[k*192+gx+128], wh5=WhhT[k*192+gx+160];
#pragma unroll
    for(int j=0;j<4;j++){
      float mk = ms[(ng*4+j)*64+k], hk = hs2[(ng*4+j)*64+k];
      ar[j][0] = fmaf(mk,wi0, fmaf(hk,wh0, ar[j][0]));
      ar[j][1] = fmaf(mk,wi1, fmaf(hk,wh1, ar[j][1]));
      az[j][0] = fmaf(mk,wi2, fmaf(hk,wh2, az[j][0]));
      az[j][1] = fmaf(mk,wi3, fmaf(hk,wh3, az[j][1]));
      anx[j][0]= fmaf(mk,wi4, anx[j][0]);
      anx[j][1]= fmaf(mk,wi5, anx[j][1]);
      anh[j][0]= fmaf(hk,wh4, anh[j][0]);
      anh[j][1]= fmaf(hk,wh5, anh[j][1]);
    }
  }
#pragma unroll
  for(int j=0;j<4;j++){
    int n = n0 + ng*4 + j;
    if(n >= N) continue;
#pragma unroll
    for(int c=0;c<2;c++){
      int d = gx + 32*c;
      float r  = sigmoidf_(ar[j][c] + bih[d]     + bhh[d]);
      float z  = sigmoidf_(az[j][c] + bih[64+d]  + bhh[64+d]);
      float nn = tanhf(anx[j][c] + bih[128+d] + r*(anh[j][c] + bhh[128+d]));
      float hv = hs2[(ng*4+j)*64+d];
      x[(size_t)n*64+d] = (1.f - z)*nn + z*hv;
    }
  }
}

// ---------------- weight transposes ----------------
__global__ void k_tr_gru(const float* __restrict__ Wih, const float* __restrict__ Whh,
                         float* __restrict__ WihT, float* __restrict__ WhhT){
  int idx = blockIdx.x*256 + threadIdx.x;
  if(idx < 192*64){
    int r = idx/64, i = idx%64;
    WihT[i*192 + r] = Wih[idx];
    WhhT[i*192 + r] = Whh[idx];
  }
}

// LSTM weights as concatenated [Wih | Whh] along k, transposed to [k][256]
__global__ void k_tr_lstmcat(const float* __restrict__ w0ih, const float* __restrict__ w0hh,
                             const float* __restrict__ w12ih, const float* __restrict__ w12hh,
                             float* __restrict__ W0cat, float* __restrict__ W12cat){
  int idx = blockIdx.x*256 + threadIdx.x;
  if(idx < 192*256){
    int k = idx / 256, r = idx % 256;
    W0cat[idx] = (k < 128) ? w0ih[r*128 + k] : w0hh[r*64 + (k - 128)];
  }
  if(idx < 2*128*256){
    int l = idx / (128*256);
    int rem = idx % (128*256);
    int k = rem / 256, r = rem % 256;
    W12cat[idx] = (k < 64) ? w12ih[((size_t)l*256 + r)*64 + k]
                           : w12hh[((size_t)l*256 + r)*64 + (k - 64)];
  }
}

// ---------------- fused Set2Set + head (R15: 4 graphs/block) ----------------
// R14 counters: k_s2s = 102us, MfmaUtil 0, VALU 13%, HBM 0.4%, Occ 10% -> L2-BW
// bound on redundant weight streams: 500 blocks x 458KB/step = 1.37GB/launch.
// G=4 graphs/block: weights loaded once, FMA'd vs 4 graphs (traffic /4 = 343MB);
// gate-reduce uses all 256 threads (t = graph*64+dim, was 64); attention fully
// wave-local (wave w owns graph w: shuffle max/sum + __shfl softmax broadcast),
// -2 syncs/step. LDS ~94KB -> 1 block/CU x 125 blocks.
__device__ __forceinline__ int lbound(const int* __restrict__ a, int n, int v){
  int lo=0, hi=n;
  while(lo<hi){ int mid=(lo+hi)>>1; if(a[mid]<v) lo=mid+1; else hi=mid; }
  return lo;
}

template<int KTOT>
__device__ __forceinline__ void lstm_layer4(
    float (*__restrict__ qcat)[320], float (*__restrict__ csl)[192],
    int xoff, int hoff, int coff,
    const float* __restrict__ Wcat, const float* __restrict__ bsum,
    f4 (*__restrict__ ps4)[256], int t)
{
  constexpr int CH = KTOT/4;
  const int kc = t >> 6, tq = t & 63;   // kc uniform per wave -> xin reads broadcast
  const float* wp = Wcat + (size_t)(kc*CH)*256 + 4*tq;
  f4 a0 = (f4){0.f,0.f,0.f,0.f}, a1 = a0, a2 = a0, a3 = a0;
#pragma unroll
  for(int i=0;i<CH;i++){
    f4 w = *(const f4*)(wp + (size_t)i*256);
    int xi = xoff + kc*CH + i;
    a0 += qcat[0][xi] * w;
    a1 += qcat[1][xi] * w;
    a2 += qcat[2][xi] * w;
    a3 += qcat[3][xi] * w;
  }
  ps4[0][t] = a0; ps4[1][t] = a1; ps4[2][t] = a2; ps4[3][t] = a3;
  __syncthreads();
  {
    const int g = t >> 6, d = t & 63;   // all 256 threads active (was 64)
    float v[4];
#pragma unroll
    for(int gate=0; gate<4; gate++){
      int G = gate*64 + d;
      int q = G >> 2, cmp = G & 3;
      float s = 0.f;
#pragma unroll
      for(int k2=0;k2<4;k2++) s += ps4[g][k2*64 + q][cmp];
      v[gate] = s + bsum[G];
    }
    float ig = sigmoidf_(v[0]);
    float fg = sigmoidf_(v[1]);
    float gg = tanhf(v[2]);
    float og = sigmoidf_(v[3]);
    float cn = fg*csl[g][coff+d] + ig*gg;
    csl[g][coff+d] = cn;
    qcat[g][hoff+d] = og*tanhf(cn);
  }
  __syncthreads();
}

__global__ __launch_bounds__(256) void k_s2s(
    const float* __restrict__ x, const int* __restrict__ gid, int N,
    const float* __restrict__ W0cat, const float* __restrict__ W12cat,
    const float* __restrict__ l0_bih, const float* __restrict__ l0_bhh,
    const float* __restrict__ l12_bih, const float* __restrict__ l12_bhh,
    const float* __restrict__ W1, const float* __restrict__ b1,
    const float* __restrict__ W2, const float* __restrict__ b2,
    float* __restrict__ y)
{
  const int b0 = blockIdx.x * 4;
  const int t = threadIdx.x;
  const int wave = t >> 6, lane = t & 63;
  __shared__ float xt[4][S2S_CAP*65];   // 66.5 KB: per-graph node cache, stride 65
  __shared__ float qcat[4][320];        // [q_star(128) | h0 | h1 | h2] per graph
  __shared__ float csl[4][192];
  __shared__ f4    ps4[4][256];         // 16 KB matvec partials (reused as head scratch)
  __shared__ float bsum[768];
  __shared__ int   sh_n0[5];

  if(t < 5) sh_n0[t] = lbound(gid, N, b0 + t);
  for(int i=t; i<4*320; i+=256) ((float*)qcat)[i] = 0.f;
  for(int i=t; i<4*192; i+=256) ((float*)csl)[i] = 0.f;
  for(int i=t; i<768; i+=256){
    int layer = i >> 8, g = i & 255;
    float bi, bh;
    if(layer == 0){ bi = l0_bih[g]; bh = l0_bhh[g]; }
    else { bi = l12_bih[(layer-1)*256+g]; bh = l12_bhh[(layer-1)*256+g]; }
    bsum[i] = bi + bh;
  }
  __syncthreads();
  const int n0w = sh_n0[wave];
  const int cntw = sh_n0[wave+1] - n0w;
  const int ccw = (cntw < S2S_CAP) ? cntw : S2S_CAP;

  // wave w caches its graph's nodes
  for(int j=0;j<ccw;j++)
    xt[wave][j*65 + lane] = x[(size_t)(n0w+j)*64 + lane];
  __syncthreads();

  for(int step=0; step<S2S_STEPS; step++){
    lstm_layer4<192>(qcat, csl,   0, 128,   0, W0cat,          bsum,     ps4, t);
    lstm_layer4<128>(qcat, csl, 128, 192,  64, W12cat,         bsum+256, ps4, t);
    lstm_layer4<128>(qcat, csl, 192, 256, 128, W12cat+128*256, bsum+512, ps4, t);

    // ---- attention: wave w handles graph b0+w, fully wave-local ----
    const float* q = qcat[wave] + 256;   // h2
    float accd = 0.f;
    if(lane < ccw){
      const float* xr = xt[wave] + lane*65;
#pragma unroll 8
      for(int k=0;k<64;k++) accd = fmaf(xr[k], q[k], accd);
    }
    float pm = (lane < ccw) ? accd : -1e30f;
    float qv = q[lane];
    for(int j = S2S_CAP; j < cntw; j++){   // fallback (practically never)
      float p = x[(size_t)(n0w+j)*64 + lane] * qv;
#pragma unroll
      for(int o=32;o;o>>=1) p += __shfl_xor(p, o, 64);
      pm = fmaxf(pm, p);
    }
#pragma unroll
    for(int o=32;o;o>>=1) pm = fmaxf(pm, __shfl_xor(pm, o, 64));
    const float mx = pm;

    float ex = (lane < ccw) ? expf(accd - mx) : 0.f;
    float exsum = ex;
#pragma unroll
    for(int o=32;o;o>>=1) exsum += __shfl_xor(exsum, o, 64);

    float racc = 0.f;
    for(int j=0;j<ccw;j++)
      racc = fmaf(__shfl(ex, j, 64), xt[wave][j*65 + lane], racc);
    for(int j = S2S_CAP; j < cntw; j++){   // fallback pass 2
      float xv = x[(size_t)(n0w+j)*64 + lane];
      float p = xv * qv;
#pragma unroll
      for(int o=32;o;o>>=1) p += __shfl_xor(p, o, 64);
      float e2 = expf(p - mx);
      exsum += e2;
      racc = fmaf(e2, xv, racc);
    }
    float inv = (exsum > 0.f) ? 1.f/exsum : 0.f;
    // new q_star = [h2 | readout]
    qcat[wave][lane]      = qcat[wave][256 + lane];
    qcat[wave][64 + lane] = racc * inv;
    __syncthreads();
  }
  // ---- head: thread (g,d) does lin1; then 48 threads do lin2 ----
  float* hh = (float*)ps4;   // reuse as [4][64]
  {
    const int g = t >> 6, d = t & 63;
    float a = b1[d];
#pragma unroll 4
    for(int k=0;k<128;k++) a = fmaf(qcat[g][k], W1[k*64+d], a);
    hh[g*64 + d] = fmaxf(a, 0.f);
  }
  __syncthreads();
  if(t < 48){
    int g = t / 12, o = t % 12;
    float out = b2[o];
#pragma unroll 4
    for(int k=0;k<64;k++) out = fmaf(hh[g*64 + k], W2[k*12+o], out);
    y[(size_t)(b0+g)*12 + o] = out;
  }
}

extern "C" void kernel_launch(void* const* d_in, const int* in_sizes, int n_in,
                              void* d_out, int out_size, void* d_ws, size_t ws_size,
                              hipStream_t stream) {
  const float* node_feat = (const float*)d_in[0];
  const float* edge_feat = (const float*)d_in[1];
  const int*   src       = (const int*)d_in[2];
  const int*   dst       = (const int*)d_in[3];
  const int*   gid       = (const int*)d_in[4];
  const float* lin0_W = (const float*)d_in[6];
  const float* lin0_b = (const float*)d_in[7];
  const float* em_W1  = (const float*)d_in[8];
  const float* em_b1  = (const float*)d_in[9];
  const float* em_W2  = (const float*)d_in[10];
  const float* em_b2  = (const float*)d_in[11];
  const float* conv_b = (const float*)d_in[12];
  const float* gru_Wih = (const float*)d_in[13];
  const float* gru_Whh = (const float*)d_in[14];
  const float* gru_bih = (const float*)d_in[15];
  const float* gru_bhh = (const float*)d_in[16];
  const float* l0_Wih = (const float*)d_in[17];
  const float* l0_Whh = (const float*)d_in[18];
  const float* l0_bih = (const float*)d_in[19];
  const float* l0_bhh = (const float*)d_in[20];
  const float* l12_Wih = (const float*)d_in[21];
  const float* l12_Whh = (const float*)d_in[22];
  const float* l12_bih = (const float*)d_in[23];
  const float* l12_bhh = (const float*)d_in[24];
  const float* lin1_W = (const float*)d_in[25];
  const float* lin1_b = (const float*)d_in[26];
  const float* lin2_W = (const float*)d_in[27];
  const float* lin2_b = (const float*)d_in[28];
  float* y = (float*)d_out;

  const int N = in_sizes[0] / 15;
  const int E = in_sizes[1] / 5;
  const int B = NGRAPH;

  char* p = (char*)d_ws;
  auto carve = [&](size_t bytes)->char* {
    char* r = p; p += (bytes + 255) & ~(size_t)255; return r;
  };
  _Float16* he_h = (_Float16*)carve((size_t)E*160*2);
  _Float16* W2T  = (_Float16*)carve((size_t)4096*160*2);
  float* x      = (float*)carve((size_t)N*64*4);
  float* agg    = (float*)carve((size_t)N*64*4);
  float* gWihT  = (float*)carve(192*64*4);
  float* gWhhT  = (float*)carve(192*64*4);
  float* W0cat  = (float*)carve(192*256*4);
  float* W12cat = (float*)carve(2*128*256*4);
  (void)ws_size; (void)n_in; (void)out_size;

  // ---- prep ----
  k_lin0<<<(N+3)/4, 256, 0, stream>>>(node_feat, lin0_W, lin0_b, x, N);
  k_edgeh<<<E, 192, 0, stream>>>(edge_feat, em_W1, em_b1, he_h, E);
  k_prepW2<<<(4096*160+255)/256, 256, 0, stream>>>(em_W2, em_b2, W2T);
  k_tr_gru<<<(192*64+255)/256, 256, 0, stream>>>(gru_Wih, gru_Whh, gWihT, gWhhT);
  k_tr_lstmcat<<<(2*128*256+255)/256, 256, 0, stream>>>(l0_Wih, l0_Whh, l12_Wih, l12_Whh,
                                                        W0cat, W12cat);
  k_zero<<<(N*64+255)/256, 256, 0, stream>>>(agg, N*64);

  // ---- message passing (k_gru2 zeroes agg for the next step) ----
  const int nblk = (E + 127) / 128;
  for(int s=0; s<MP_STEPS; s++){
    k_fmsg<<<nblk, 512, 0, stream>>>(he_h, W2T, x, src, dst, agg, E);
    k_gru2<<<(N+31)/32, 256, 0, stream>>>(x, agg, conv_b, gWihT, gWhhT, gru_bih, gru_bhh, N);
  }

  // ---- fused set2set + head: 4 graphs per block ----
  k_s2s<<<B/4, 256, 0, stream>>>(x, gid, N,
                                 W0cat, W12cat, l0_bih, l0_bhh,
                                 l12_bih, l12_bhh,
                                 lin1_W, lin1_b, lin2_W, lin2_b, y);
}